// Round 1
// baseline (257.537 us; speedup 1.0000x reference)
//
#include <hip/hip_runtime.h>
#include <hip/hip_cooperative_groups.h>

namespace cg = cooperative_groups;

#define N 4096
#define NCLS 10
#define RPB 16                 // rows per chunk
#define NCHUNK (N / RPB)       // 256 row chunks
#define NSLICE 2               // 2048-column slices
#define CAPS 64                // candidate slots per (row, slice); E=32
#define THRESH 0.015625f       // 1/64: E[cands/row]=64
#define CRG 16                 // fold output groups
#define CRC (NCHUNK / CRG)     // 16 chunks folded per group
#define NBLK (NCHUNK * NSLICE) // 512 blocks (cooperative grid)
#define SELBLK (N / 4)         // 1024 row-select blocks (fallback path)
#define FOLDBLK (CRG * 4)      // 64 fold blocks
#define FINBLK 16              // final blocks (256 cols each)

__device__ __forceinline__ bool lessvi(float v1, int i1, float v2, int i2) {
    return (v1 < v2) || (v1 == v2 && i1 < i2);
}

// stable top-4 insertion of (vv, ci), lexicographic (value, index)
__device__ __forceinline__ void insert4(float vv, int ci, float tv[4], int ti[4]) {
    if (lessvi(vv, ci, tv[3], ti[3])) {
        tv[3] = vv; ti[3] = ci;
#pragma unroll
        for (int q2 = 3; q2 > 0; --q2) {
            const bool sw = lessvi(tv[q2], ti[q2], tv[q2 - 1], ti[q2 - 1]);
            const float av = tv[q2 - 1]; const int ai = ti[q2 - 1];
            tv[q2 - 1] = sw ? tv[q2] : av;
            ti[q2 - 1] = sw ? ti[q2] : ai;
            tv[q2]     = sw ? av : tv[q2];
            ti[q2]     = sw ? ai : ti[q2];
        }
    }
}

// ================= fused cooperative kernel =================
// Phase 1 (all 512 blocks): verbatim stream2d body.
// grid.sync()
// Phase 2: select top-4 (8 rows per block) + fold pdiff (blocks 0..63).
// grid.sync()
// Phase 3 (blocks 0..15): verbatim final_k body.
__global__ __launch_bounds__(256, 4) void lmnn_fused(const float* __restrict__ D,
                                                     const int* __restrict__ labels,
                                                     float* __restrict__ pdiff,
                                                     float* __restrict__ cand_v,
                                                     int* __restrict__ cand_i,
                                                     int* __restrict__ cand_cnt,
                                                     float* __restrict__ cdiff,
                                                     float* __restrict__ pd_sum,
                                                     float* __restrict__ a_cnt,
                                                     float* __restrict__ out) {
    __shared__ int    scnt[RPB];
    __shared__ float  lv[RPB][CAPS];
    __shared__ int    li[RPB][CAPS];
    __shared__ int    cls[NCLS];
    __shared__ double red[256];

    const int tid  = threadIdx.x;
    const int lane = tid & 63;
    const int wave = tid >> 6;

    // ---------------- phase 1: stream D ----------------
    {
        const int slice = blockIdx.x & (NSLICE - 1);
        const int chunk = blockIdx.x >> 1;
        const int r0    = chunk * RPB;
        const int c0    = slice * 2048 + tid * 4;      // first quad
        const int c1    = c0 + 1024;                   // second quad

        if (blockIdx.x == 0 && tid == 0) out[0] = 0.f;
        if (tid < RPB) scnt[tid] = 0;
        __syncthreads();

        const int4 clA = *(const int4*)(labels + c0);
        const int4 clB = *(const int4*)(labels + c1);
        float4 dA = {0.f, 0.f, 0.f, 0.f};
        float4 dB = {0.f, 0.f, 0.f, 0.f};

        const float4* rb = (const float4*)(D + (size_t)r0 * N + slice * 2048);
        float4 bufA[3], bufB[3];
        bufA[0] = rb[tid];        bufB[0] = rb[tid + 256];
        bufA[1] = rb[1024 + tid]; bufB[1] = rb[1024 + tid + 256];

#pragma unroll
        for (int r = 0; r < RPB; ++r) {
            if (r + 2 < RPB) {
                bufA[(r + 2) % 3] = rb[(size_t)(r + 2) * 1024 + tid];
                bufB[(r + 2) % 3] = rb[(size_t)(r + 2) * 1024 + tid + 256];
            }
            const float4 cA = bufA[r % 3];
            const float4 cB = bufB[r % 3];
            const int rowlab = labels[r0 + r];

            dA.x += (clA.x != rowlab) ? cA.x : 0.f;
            dA.y += (clA.y != rowlab) ? cA.y : 0.f;
            dA.z += (clA.z != rowlab) ? cA.z : 0.f;
            dA.w += (clA.w != rowlab) ? cA.w : 0.f;
            dB.x += (clB.x != rowlab) ? cB.x : 0.f;
            dB.y += (clB.y != rowlab) ? cB.y : 0.f;
            dB.z += (clB.z != rowlab) ? cB.z : 0.f;
            dB.w += (clB.w != rowlab) ? cB.w : 0.f;

            const float va[4] = {cA.x, cA.y, cA.z, cA.w};
            const float vb[4] = {cB.x, cB.y, cB.z, cB.w};
#pragma unroll
            for (int e = 0; e < 4; ++e) {
                if (va[e] < THRESH) {                  // rare (~1/64)
                    const int idx = atomicAdd(&scnt[r], 1);
                    if (idx < CAPS) { lv[r][idx] = va[e]; li[r][idx] = c0 + e; }
                }
            }
#pragma unroll
            for (int e = 0; e < 4; ++e) {
                if (vb[e] < THRESH) {
                    const int idx = atomicAdd(&scnt[r], 1);
                    if (idx < CAPS) { lv[r][idx] = vb[e]; li[r][idx] = c1 + e; }
                }
            }
        }

        *(float4*)(pdiff + (size_t)chunk * N + c0) = dA;
        *(float4*)(pdiff + (size_t)chunk * N + c1) = dB;

        __syncthreads();   // all candidate LDS traffic done
        for (int rr = wave; rr < RPB; rr += 4) {
            const int c   = scnt[rr];
            const int row = r0 + rr;
            if (lane == 0) cand_cnt[(size_t)row * NSLICE + slice] = c;
            if (lane < (c < CAPS ? c : CAPS)) {
                const size_t slot = (size_t)row * (NSLICE * CAPS) + slice * CAPS + lane;
                cand_v[slot] = lv[rr][lane];
                cand_i[slot] = li[rr][lane];
            }
        }
    }

    cg::this_grid().sync();

    // ---------------- phase 2: select (8 rows/block) + fold ----------------
    {
#pragma unroll
        for (int uu = 0; uu < 2; ++uu) {
            const int row = blockIdx.x * 8 + uu * 4 + wave;

            const int2 cnt2 = *(const int2*)(cand_cnt + (size_t)row * NSLICE);
            const int total = cnt2.x + cnt2.y;
            const bool ok = (total >= 4) && (cnt2.x <= CAPS) && (cnt2.y <= CAPS);

            float tv[4] = {INFINITY, INFINITY, INFINITY, INFINITY};
            int   ti[4] = {0x7ffffff0, 0x7ffffff1, 0x7ffffff2, 0x7ffffff3};

            if (ok) {
                const int cs2[2] = {cnt2.x, cnt2.y};
#pragma unroll
                for (int s = 0; s < 2; ++s) {
                    const size_t base = (size_t)row * (NSLICE * CAPS) + s * CAPS;
                    for (int k = lane; k < cs2[s]; k += 64)
                        insert4(cand_v[base + k], cand_i[base + k], tv, ti);
                }
            } else {
                // exact fallback: scan the whole row (coalesced)
                const float4* rp4 = (const float4*)(D + (size_t)row * N);
                for (int s = 0; s < 16; ++s) {
                    const float4 q = rp4[s * 64 + lane];
                    const int cc = (s * 64 + lane) * 4;
                    insert4(q.x, cc, tv, ti);
                    insert4(q.y, cc + 1, tv, ti);
                    insert4(q.z, cc + 2, tv, ti);
                    insert4(q.w, cc + 3, tv, ti);
                }
            }

            // butterfly merge of sorted-4 lists across the 64-lane wave
#pragma unroll
            for (int off = 1; off < 64; off <<= 1) {
                float yv[4]; int yi[4];
#pragma unroll
                for (int k = 0; k < 4; ++k) {
                    yv[k] = __shfl_xor(tv[k], off);
                    yi[k] = __shfl_xor(ti[k], off);
                }
                float rv[4]; int ri[4];
#pragma unroll
                for (int k = 0; k < 4; ++k) {
                    const bool tm = lessvi(tv[0], ti[0], yv[0], yi[0]);
                    rv[k] = tm ? tv[0] : yv[0];
                    ri[k] = tm ? ti[0] : yi[0];
#pragma unroll
                    for (int q2 = 0; q2 < 3; ++q2) {
                        tv[q2] = tm ? tv[q2 + 1] : tv[q2];
                        ti[q2] = tm ? ti[q2 + 1] : ti[q2];
                        yv[q2] = tm ? yv[q2]     : yv[q2 + 1];
                        yi[q2] = tm ? yi[q2]     : yi[q2 + 1];
                    }
                }
#pragma unroll
                for (int k = 0; k < 4; ++k) { tv[k] = rv[k]; ti[k] = ri[k]; }
            }

            if (lane == 0) {
                const int li2 = labels[row];
                float pd = 0.f, a = 0.f;
#pragma unroll
                for (int m = 0; m < 4; ++m) {
                    const int j = ti[m];
                    if (j != row && labels[j] == li2) { pd += tv[m]; a += 1.f; }
                }
                pd_sum[row] = pd;
                a_cnt[row]  = a;
            }
        }

        if (blockIdx.x < FOLDBLK) {
            const int fb   = blockIdx.x;
            const int tile = fb & 3;
            const int g    = fb >> 2;
            const int col  = tile * 1024 + tid * 4;
            float4 acc = {0.f, 0.f, 0.f, 0.f};
#pragma unroll 8
            for (int ch = 0; ch < CRC; ++ch) {
                const float4 v = *(const float4*)(pdiff + (size_t)(g * CRC + ch) * N + col);
                acc.x += v.x; acc.y += v.y; acc.z += v.z; acc.w += v.w;
            }
            *(float4*)(cdiff + (size_t)g * N + col) = acc;
        }
    }

    cg::this_grid().sync();

    // ---------------- phase 3: final ----------------
    if (blockIdx.x < FINBLK) {
        const int col = blockIdx.x * 256 + tid;

        if (tid < NCLS) cls[tid] = 0;
        __syncthreads();
        for (int i = tid; i < N; i += 256) atomicAdd(&cls[labels[i]], 1);
        __syncthreads();

        float cs = 0.f;
#pragma unroll
        for (int g = 0; g < CRG; ++g)                 // coalesced: consecutive cols
            cs += cdiff[(size_t)g * N + col];

        const int lab = labels[col];
        const double pd = (double)pd_sum[col];
        const double a  = (double)a_cnt[col];
        const double cd = (double)(N - cls[lab]);
        red[tid] = pd + cd * (pd + a) - a * (double)cs;   // pull_i + push_i

        __syncthreads();
        for (int s = 128; s > 0; s >>= 1) {
            if (tid < s) red[tid] += red[tid + s];
            __syncthreads();
        }
        if (tid == 0) atomicAdd(out, (float)(0.5 * red[0]));
    }
}

// ================= fallback: original 3-kernel path =================
__global__ __launch_bounds__(256) void stream2d(const float* __restrict__ D,
                                                const int* __restrict__ labels,
                                                float* __restrict__ pdiff,
                                                float* __restrict__ cand_v,
                                                int* __restrict__ cand_i,
                                                int* __restrict__ cand_cnt,
                                                float* __restrict__ out) {
    __shared__ int   scnt[RPB];
    __shared__ float lv[RPB][CAPS];
    __shared__ int   li[RPB][CAPS];

    const int tid   = threadIdx.x;
    const int lane  = tid & 63;
    const int wave  = tid >> 6;
    const int slice = blockIdx.x & (NSLICE - 1);
    const int chunk = blockIdx.x >> 1;
    const int r0    = chunk * RPB;
    const int c0    = slice * 2048 + tid * 4;
    const int c1    = c0 + 1024;

    if (blockIdx.x == 0 && tid == 0) out[0] = 0.f;
    if (tid < RPB) scnt[tid] = 0;
    __syncthreads();

    const int4 clA = *(const int4*)(labels + c0);
    const int4 clB = *(const int4*)(labels + c1);
    float4 dA = {0.f, 0.f, 0.f, 0.f};
    float4 dB = {0.f, 0.f, 0.f, 0.f};

    const float4* rb = (const float4*)(D + (size_t)r0 * N + slice * 2048);
    float4 bufA[3], bufB[3];
    bufA[0] = rb[tid];        bufB[0] = rb[tid + 256];
    bufA[1] = rb[1024 + tid]; bufB[1] = rb[1024 + tid + 256];

#pragma unroll
    for (int r = 0; r < RPB; ++r) {
        if (r + 2 < RPB) {
            bufA[(r + 2) % 3] = rb[(size_t)(r + 2) * 1024 + tid];
            bufB[(r + 2) % 3] = rb[(size_t)(r + 2) * 1024 + tid + 256];
        }
        const float4 cA = bufA[r % 3];
        const float4 cB = bufB[r % 3];
        const int rowlab = labels[r0 + r];

        dA.x += (clA.x != rowlab) ? cA.x : 0.f;
        dA.y += (clA.y != rowlab) ? cA.y : 0.f;
        dA.z += (clA.z != rowlab) ? cA.z : 0.f;
        dA.w += (clA.w != rowlab) ? cA.w : 0.f;
        dB.x += (clB.x != rowlab) ? cB.x : 0.f;
        dB.y += (clB.y != rowlab) ? cB.y : 0.f;
        dB.z += (clB.z != rowlab) ? cB.z : 0.f;
        dB.w += (clB.w != rowlab) ? cB.w : 0.f;

        const float va[4] = {cA.x, cA.y, cA.z, cA.w};
        const float vb[4] = {cB.x, cB.y, cB.z, cB.w};
#pragma unroll
        for (int e = 0; e < 4; ++e) {
            if (va[e] < THRESH) {
                const int idx = atomicAdd(&scnt[r], 1);
                if (idx < CAPS) { lv[r][idx] = va[e]; li[r][idx] = c0 + e; }
            }
        }
#pragma unroll
        for (int e = 0; e < 4; ++e) {
            if (vb[e] < THRESH) {
                const int idx = atomicAdd(&scnt[r], 1);
                if (idx < CAPS) { lv[r][idx] = vb[e]; li[r][idx] = c1 + e; }
            }
        }
    }

    *(float4*)(pdiff + (size_t)chunk * N + c0) = dA;
    *(float4*)(pdiff + (size_t)chunk * N + c1) = dB;

    __syncthreads();
    for (int rr = wave; rr < RPB; rr += 4) {
        const int c   = scnt[rr];
        const int row = r0 + rr;
        if (lane == 0) cand_cnt[(size_t)row * NSLICE + slice] = c;
        if (lane < (c < CAPS ? c : CAPS)) {
            const size_t slot = (size_t)row * (NSLICE * CAPS) + slice * CAPS + lane;
            cand_v[slot] = lv[rr][lane];
            cand_i[slot] = li[rr][lane];
        }
    }
}

__global__ __launch_bounds__(256) void select_fold(const float* __restrict__ D,
                                                   const int* __restrict__ labels,
                                                   const float* __restrict__ cand_v,
                                                   const int* __restrict__ cand_i,
                                                   const int* __restrict__ cand_cnt,
                                                   const float* __restrict__ pdiff,
                                                   float* __restrict__ pd_sum,
                                                   float* __restrict__ a_cnt,
                                                   float* __restrict__ cdiff) {
    if (blockIdx.x >= SELBLK) {
        const int fb   = blockIdx.x - SELBLK;
        const int tile = fb & 3;
        const int g    = fb >> 2;
        const int col  = tile * 1024 + threadIdx.x * 4;
        float4 acc = {0.f, 0.f, 0.f, 0.f};
#pragma unroll 8
        for (int ch = 0; ch < CRC; ++ch) {
            const float4 v = *(const float4*)(pdiff + (size_t)(g * CRC + ch) * N + col);
            acc.x += v.x; acc.y += v.y; acc.z += v.z; acc.w += v.w;
        }
        *(float4*)(cdiff + (size_t)g * N + col) = acc;
        return;
    }

    const int lane = threadIdx.x & 63;
    const int wave = threadIdx.x >> 6;
    const int row  = blockIdx.x * 4 + wave;

    const int2 cnt2 = *(const int2*)(cand_cnt + (size_t)row * NSLICE);
    const int total = cnt2.x + cnt2.y;
    const bool ok = (total >= 4) && (cnt2.x <= CAPS) && (cnt2.y <= CAPS);

    float tv[4] = {INFINITY, INFINITY, INFINITY, INFINITY};
    int   ti[4] = {0x7ffffff0, 0x7ffffff1, 0x7ffffff2, 0x7ffffff3};

    if (ok) {
        const int cs2[2] = {cnt2.x, cnt2.y};
#pragma unroll
        for (int s = 0; s < 2; ++s) {
            const size_t base = (size_t)row * (NSLICE * CAPS) + s * CAPS;
            for (int k = lane; k < cs2[s]; k += 64)
                insert4(cand_v[base + k], cand_i[base + k], tv, ti);
        }
    } else {
        const float4* rp4 = (const float4*)(D + (size_t)row * N);
        for (int s = 0; s < 16; ++s) {
            const float4 q = rp4[s * 64 + lane];
            const int cc = (s * 64 + lane) * 4;
            insert4(q.x, cc, tv, ti);
            insert4(q.y, cc + 1, tv, ti);
            insert4(q.z, cc + 2, tv, ti);
            insert4(q.w, cc + 3, tv, ti);
        }
    }

#pragma unroll
    for (int off = 1; off < 64; off <<= 1) {
        float yv[4]; int yi[4];
#pragma unroll
        for (int k = 0; k < 4; ++k) {
            yv[k] = __shfl_xor(tv[k], off);
            yi[k] = __shfl_xor(ti[k], off);
        }
        float rv[4]; int ri[4];
#pragma unroll
        for (int k = 0; k < 4; ++k) {
            const bool tm = lessvi(tv[0], ti[0], yv[0], yi[0]);
            rv[k] = tm ? tv[0] : yv[0];
            ri[k] = tm ? ti[0] : yi[0];
#pragma unroll
            for (int q2 = 0; q2 < 3; ++q2) {
                tv[q2] = tm ? tv[q2 + 1] : tv[q2];
                ti[q2] = tm ? ti[q2 + 1] : ti[q2];
                yv[q2] = tm ? yv[q2]     : yv[q2 + 1];
                yi[q2] = tm ? yi[q2]     : yi[q2 + 1];
            }
        }
#pragma unroll
        for (int k = 0; k < 4; ++k) { tv[k] = rv[k]; ti[k] = ri[k]; }
    }

    if (lane == 0) {
        const int li2 = labels[row];
        float pd = 0.f, a = 0.f;
#pragma unroll
        for (int m = 0; m < 4; ++m) {
            const int j = ti[m];
            if (j != row && labels[j] == li2) { pd += tv[m]; a += 1.f; }
        }
        pd_sum[row] = pd;
        a_cnt[row]  = a;
    }
}

__global__ __launch_bounds__(256) void final_k(const float* __restrict__ cdiff,
                                               const int* __restrict__ labels,
                                               const float* __restrict__ pd_sum,
                                               const float* __restrict__ a_cnt,
                                               float* __restrict__ out) {
    __shared__ int    cnt[NCLS];
    __shared__ double red[256];
    const int tid = threadIdx.x;
    const int col = blockIdx.x * 256 + tid;

    if (tid < NCLS) cnt[tid] = 0;
    __syncthreads();
    for (int i = tid; i < N; i += 256) atomicAdd(&cnt[labels[i]], 1);
    __syncthreads();

    float cs = 0.f;
#pragma unroll
    for (int g = 0; g < CRG; ++g)
        cs += cdiff[(size_t)g * N + col];

    const int li = labels[col];
    const double pd = (double)pd_sum[col];
    const double a  = (double)a_cnt[col];
    const double cd = (double)(N - cnt[li]);
    red[tid] = pd + cd * (pd + a) - a * (double)cs;

    __syncthreads();
    for (int s = 128; s > 0; s >>= 1) {
        if (tid < s) red[tid] += red[tid + s];
        __syncthreads();
    }
    if (tid == 0) atomicAdd(out, (float)(0.5 * red[0]));
}

extern "C" void kernel_launch(void* const* d_in, const int* in_sizes, int n_in,
                              void* d_out, int out_size, void* d_ws, size_t ws_size,
                              hipStream_t stream) {
    const float* D      = (const float*)d_in[0];
    const int*   labels = (const int*)d_in[1];
    float*       out    = (float*)d_out;

    float* pdiff    = (float*)d_ws;                              // 256*4096 f = 4 MB
    float* cdiff    = pdiff + (size_t)NCHUNK * N;                // 16*4096 f
    float* pd_sum   = cdiff + (size_t)CRG * N;                   // 4096 f
    float* a_cnt    = pd_sum + N;                                // 4096 f
    float* cand_v   = a_cnt + N;                                 // 4096*128 f
    int*   cand_i   = (int*)(cand_v + (size_t)N * NSLICE * CAPS);// 4096*128 i
    int*   cand_cnt = cand_i + (size_t)N * NSLICE * CAPS;        // 4096*2 i

    void* kargs[] = {&D, &labels, &pdiff, &cand_v, &cand_i, &cand_cnt,
                     &cdiff, &pd_sum, &a_cnt, &out};
    hipError_t e = hipLaunchCooperativeKernel(lmnn_fused, dim3(NBLK), dim3(256),
                                              kargs, 0u, stream);
    if (e != hipSuccess) {
        // fallback: original verified 3-kernel path
        stream2d<<<NBLK, 256, 0, stream>>>(D, labels, pdiff, cand_v, cand_i,
                                           cand_cnt, out);
        select_fold<<<SELBLK + FOLDBLK, 256, 0, stream>>>(D, labels, cand_v, cand_i,
                                                          cand_cnt, pdiff, pd_sum,
                                                          a_cnt, cdiff);
        final_k<<<FINBLK, 256, 0, stream>>>(cdiff, labels, pd_sum, a_cnt, out);
    }
}

// Round 2
// 105.606 us; speedup vs baseline: 2.4387x; 2.4387x over previous
//
#include <hip/hip_runtime.h>

#define N 4096
#define NCLS 10
#define RPB 16                 // rows per chunk
#define NCHUNK (N / RPB)       // 256 row chunks
#define NSLICE 4               // 1024-column slices (R2: was 2; 4 blocks/CU now)
#define SLICEW 1024            // columns per slice
#define CAPS 64                // candidate slots per (row, slice); E=16 at 1024 cols
#define THRESH 0.015625f       // 1/64: E[cands/row]=64
#define CRG 16                 // fold output groups
#define CRC (NCHUNK / CRG)     // 16 chunks folded per group
#define SELBLK (N / 4)         // 1024 row-select blocks
#define FOLDBLK (CRG * 4)      // 64 fold blocks
#define FINBLK 16              // final blocks (256 cols each)

__device__ __forceinline__ bool lessvi(float v1, int i1, float v2, int i2) {
    return (v1 < v2) || (v1 == v2 && i1 < i2);
}

// stable top-4 insertion of (vv, ci), lexicographic (value, index)
__device__ __forceinline__ void insert4(float vv, int ci, float tv[4], int ti[4]) {
    if (lessvi(vv, ci, tv[3], ti[3])) {
        tv[3] = vv; ti[3] = ci;
#pragma unroll
        for (int q2 = 3; q2 > 0; --q2) {
            const bool sw = lessvi(tv[q2], ti[q2], tv[q2 - 1], ti[q2 - 1]);
            const float av = tv[q2 - 1]; const int ai = ti[q2 - 1];
            tv[q2 - 1] = sw ? tv[q2] : av;
            ti[q2 - 1] = sw ? ti[q2] : ai;
            tv[q2]     = sw ? av : tv[q2];
            ti[q2]     = sw ? ai : ti[q2];
        }
    }
}

// ---------------- Kernel 1: streaming pass over D (R2 config) ----------------
// Block = (16-row chunk) x (1024-col slice); 1024 blocks -> 4 blocks/CU,
// 16 waves/CU (50% occupancy, was 25%). Thread owns ONE float4 per row,
// rows pipelined 4 deep (4 loads in flight steady-state).
// Diff accumulate + threshold test; candidates staged in LDS, flushed once.
// Block 0 zeroes out[0] (final accumulates via atomicAdd; kernel-boundary
// ordering — NO device fences / grid.sync, they storm multi-XCD L2 (R1/R9)).
__global__ __launch_bounds__(256) void stream2d(const float* __restrict__ D,
                                                const int* __restrict__ labels,
                                                float* __restrict__ pdiff,
                                                float* __restrict__ cand_v,
                                                int* __restrict__ cand_i,
                                                int* __restrict__ cand_cnt,
                                                float* __restrict__ out) {
    __shared__ int   scnt[RPB];
    __shared__ float lv[RPB][CAPS];
    __shared__ int   li[RPB][CAPS];

    const int tid   = threadIdx.x;
    const int lane  = tid & 63;
    const int wave  = tid >> 6;
    const int slice = blockIdx.x & (NSLICE - 1);
    const int chunk = blockIdx.x >> 2;
    const int r0    = chunk * RPB;
    const int c0    = slice * SLICEW + tid * 4;    // this thread's 4 columns

    if (blockIdx.x == 0 && tid == 0) out[0] = 0.f;
    if (tid < RPB) scnt[tid] = 0;
    __syncthreads();

    const int4 clA = *(const int4*)(labels + c0);
    float4 dA = {0.f, 0.f, 0.f, 0.f};

    // row-major walk: rb[r*1024 + tid] is row r0+r, cols c0..c0+3
    const float4* rb = (const float4*)(D + (size_t)r0 * N + slice * SLICEW);
    float4 buf[4];
    buf[0] = rb[tid];
    buf[1] = rb[1024 + tid];
    buf[2] = rb[2048 + tid];
    buf[3] = rb[3072 + tid];

#pragma unroll
    for (int r = 0; r < RPB; ++r) {
        const float4 cA = buf[r & 3];
        if (r + 4 < RPB)
            buf[r & 3] = rb[(size_t)(r + 4) * 1024 + tid];

        const int rowlab = labels[r0 + r];

        dA.x += (clA.x != rowlab) ? cA.x : 0.f;
        dA.y += (clA.y != rowlab) ? cA.y : 0.f;
        dA.z += (clA.z != rowlab) ? cA.z : 0.f;
        dA.w += (clA.w != rowlab) ? cA.w : 0.f;

        const float va[4] = {cA.x, cA.y, cA.z, cA.w};
#pragma unroll
        for (int e = 0; e < 4; ++e) {
            if (va[e] < THRESH) {                  // rare (~1/64)
                const int idx = atomicAdd(&scnt[r], 1);
                if (idx < CAPS) { lv[r][idx] = va[e]; li[r][idx] = c0 + e; }
            }
        }
    }

    // per-chunk column diff partials (this block's 1024-col segment)
    *(float4*)(pdiff + (size_t)chunk * N + c0) = dA;

    __syncthreads();   // all candidate LDS traffic done
    // flush candidates: wave w handles rows w, w+4, w+8, w+12
    for (int rr = wave; rr < RPB; rr += 4) {
        const int c   = scnt[rr];
        const int row = r0 + rr;
        if (lane == 0) cand_cnt[(size_t)row * NSLICE + slice] = c;
        if (lane < (c < CAPS ? c : CAPS)) {
            const size_t slot = (size_t)row * (NSLICE * CAPS) + slice * CAPS + lane;
            cand_v[slot] = lv[rr][lane];
            cand_i[slot] = li[rr][lane];
        }
    }
}

// ---------------- Kernel 2: select top-4 per row + fold diff partials ----------------
// Blocks [0, SELBLK): one wave per row, stable top-4 from candidates
// (exact full-row fallback if overflow / total<4).
// Blocks [SELBLK, SELBLK+FOLDBLK): fold pdiff 256 chunks -> 16 groups.
__global__ __launch_bounds__(256) void select_fold(const float* __restrict__ D,
                                                   const int* __restrict__ labels,
                                                   const float* __restrict__ cand_v,
                                                   const int* __restrict__ cand_i,
                                                   const int* __restrict__ cand_cnt,
                                                   const float* __restrict__ pdiff,
                                                   float* __restrict__ pd_sum,
                                                   float* __restrict__ a_cnt,
                                                   float* __restrict__ cdiff) {
    if (blockIdx.x >= SELBLK) {
        const int fb   = blockIdx.x - SELBLK;
        const int tile = fb & 3;
        const int g    = fb >> 2;
        const int col  = tile * 1024 + threadIdx.x * 4;
        float4 acc = {0.f, 0.f, 0.f, 0.f};
#pragma unroll 8
        for (int ch = 0; ch < CRC; ++ch) {
            const float4 v = *(const float4*)(pdiff + (size_t)(g * CRC + ch) * N + col);
            acc.x += v.x; acc.y += v.y; acc.z += v.z; acc.w += v.w;
        }
        *(float4*)(cdiff + (size_t)g * N + col) = acc;
        return;
    }

    const int lane = threadIdx.x & 63;
    const int wave = threadIdx.x >> 6;
    const int row  = blockIdx.x * 4 + wave;

    const int4 cnt4 = *(const int4*)(cand_cnt + (size_t)row * NSLICE);
    const int total = cnt4.x + cnt4.y + cnt4.z + cnt4.w;
    const bool ok = (total >= 4) && (cnt4.x <= CAPS) && (cnt4.y <= CAPS) &&
                    (cnt4.z <= CAPS) && (cnt4.w <= CAPS);

    float tv[4] = {INFINITY, INFINITY, INFINITY, INFINITY};
    int   ti[4] = {0x7ffffff0, 0x7ffffff1, 0x7ffffff2, 0x7ffffff3};

    if (ok) {
        const int cs4[4] = {cnt4.x, cnt4.y, cnt4.z, cnt4.w};
#pragma unroll
        for (int s = 0; s < NSLICE; ++s) {
            const size_t base = (size_t)row * (NSLICE * CAPS) + s * CAPS;
            for (int k = lane; k < cs4[s]; k += 64)
                insert4(cand_v[base + k], cand_i[base + k], tv, ti);
        }
    } else {
        // exact fallback: scan the whole row (coalesced)
        const float4* rp4 = (const float4*)(D + (size_t)row * N);
        for (int s = 0; s < 16; ++s) {
            const float4 q = rp4[s * 64 + lane];
            const int cc = (s * 64 + lane) * 4;
            insert4(q.x, cc, tv, ti);
            insert4(q.y, cc + 1, tv, ti);
            insert4(q.z, cc + 2, tv, ti);
            insert4(q.w, cc + 3, tv, ti);
        }
    }

    // butterfly merge of sorted-4 lists across the 64-lane wave
#pragma unroll
    for (int off = 1; off < 64; off <<= 1) {
        float yv[4]; int yi[4];
#pragma unroll
        for (int k = 0; k < 4; ++k) {
            yv[k] = __shfl_xor(tv[k], off);
            yi[k] = __shfl_xor(ti[k], off);
        }
        float rv[4]; int ri[4];
#pragma unroll
        for (int k = 0; k < 4; ++k) {
            const bool tm = lessvi(tv[0], ti[0], yv[0], yi[0]);
            rv[k] = tm ? tv[0] : yv[0];
            ri[k] = tm ? ti[0] : yi[0];
#pragma unroll
            for (int q2 = 0; q2 < 3; ++q2) {
                tv[q2] = tm ? tv[q2 + 1] : tv[q2];
                ti[q2] = tm ? ti[q2 + 1] : ti[q2];
                yv[q2] = tm ? yv[q2]     : yv[q2 + 1];
                yi[q2] = tm ? yi[q2]     : yi[q2 + 1];
            }
        }
#pragma unroll
        for (int k = 0; k < 4; ++k) { tv[k] = rv[k]; ti[k] = ri[k]; }
    }

    if (lane == 0) {
        const int li2 = labels[row];
        float pd = 0.f, a = 0.f;
#pragma unroll
        for (int m = 0; m < 4; ++m) {
            const int j = ti[m];
            if (j != row && labels[j] == li2) { pd += tv[m]; a += 1.f; }
        }
        pd_sum[row] = pd;
        a_cnt[row]  = a;
    }
}

// ---------------- Kernel 3: final (parallel, 16 blocks x 256 cols) ----------------
// cs_i = sum_g cdiff[g][i]; contrib_i = pd_i + (N-cnt[L_i])*(pd_i+a_i) - a_i*cs_i
// Block-reduce in double, one fp32 atomicAdd of 0.5*partial per block.
__global__ __launch_bounds__(256) void final_k(const float* __restrict__ cdiff,
                                               const int* __restrict__ labels,
                                               const float* __restrict__ pd_sum,
                                               const float* __restrict__ a_cnt,
                                               float* __restrict__ out) {
    __shared__ int    cnt[NCLS];
    __shared__ double red[256];
    const int tid = threadIdx.x;
    const int col = blockIdx.x * 256 + tid;

    if (tid < NCLS) cnt[tid] = 0;
    __syncthreads();
    for (int i = tid; i < N; i += 256) atomicAdd(&cnt[labels[i]], 1);
    __syncthreads();

    float cs = 0.f;
#pragma unroll
    for (int g = 0; g < CRG; ++g)                 // coalesced: consecutive cols
        cs += cdiff[(size_t)g * N + col];

    const int li = labels[col];
    const double pd = (double)pd_sum[col];
    const double a  = (double)a_cnt[col];
    const double cd = (double)(N - cnt[li]);
    red[tid] = pd + cd * (pd + a) - a * (double)cs;   // pull_i + push_i

    __syncthreads();
    for (int s = 128; s > 0; s >>= 1) {
        if (tid < s) red[tid] += red[tid + s];
        __syncthreads();
    }
    if (tid == 0) atomicAdd(out, (float)(0.5 * red[0]));
}

extern "C" void kernel_launch(void* const* d_in, const int* in_sizes, int n_in,
                              void* d_out, int out_size, void* d_ws, size_t ws_size,
                              hipStream_t stream) {
    const float* D      = (const float*)d_in[0];
    const int*   labels = (const int*)d_in[1];
    float*       out    = (float*)d_out;

    float* pdiff    = (float*)d_ws;                              // 256*4096 f = 4 MB
    float* cdiff    = pdiff + (size_t)NCHUNK * N;                // 16*4096 f
    float* pd_sum   = cdiff + (size_t)CRG * N;                   // 4096 f
    float* a_cnt    = pd_sum + N;                                // 4096 f
    float* cand_v   = a_cnt + N;                                 // 4096*256 f = 4 MB
    int*   cand_i   = (int*)(cand_v + (size_t)N * NSLICE * CAPS);// 4096*256 i = 4 MB
    int*   cand_cnt = cand_i + (size_t)N * NSLICE * CAPS;        // 4096*4 i

    stream2d<<<NCHUNK * NSLICE, 256, 0, stream>>>(D, labels, pdiff, cand_v, cand_i,
                                                  cand_cnt, out);
    select_fold<<<SELBLK + FOLDBLK, 256, 0, stream>>>(D, labels, cand_v, cand_i, cand_cnt,
                                                      pdiff, pd_sum, a_cnt, cdiff);
    final_k<<<FINBLK, 256, 0, stream>>>(cdiff, labels, pd_sum, a_cnt, out);
}